// Round 4
// baseline (1297.607 us; speedup 1.0000x reference)
//
#include <hip/hip_runtime.h>
#include <math.h>

#define NV    49
#define Himg  256
#define Wimg  256
#define RW    240
#define RWH   (RW*RW)          // 57600
#define NPIX  (4*RWH)          // 230400
#define ROWF  (Wimg*3)         // 768 floats per image row
#define IMGF  (Himg*Wimg*3)    // 196608 floats per view image
#define BLK   64
#define NBLK  (NPIX/BLK)       // 3600

#define CL7(a) ((a)<0?0:((a)>6?6:(a)))

// 49-wide register vectors: vector SSA values cannot be demoted to scratch,
// and every index below is a compile-time constant after unrolling.
typedef float vf49 __attribute__((ext_vector_type(49)));

// ---------------------------------------------------------------------------
// One thread per pixel, one wave per block. Warp 49 views + color loss +
// angular gauss + stable rank + tail + grad loss, fully in registers.
// ---------------------------------------------------------------------------
__global__ __launch_bounds__(BLK) void loss_kernel(
    const float* __restrict__ pred, const float* __restrict__ x,
    const float* __restrict__ y, const int* __restrict__ epoch_p,
    double* __restrict__ acc)
{
    const int tid = threadIdx.x;

    // XCD band swizzle: XCD k (= bid%8) gets a contiguous band of blocks
    int lb  = (blockIdx.x & 7) * (NBLK / 8) + (blockIdx.x >> 3);
    int pid = lb * BLK + tid;              // 0..230399 (exact grid)
    int b   = pid / RWH;
    int rem = pid - b * RWH;
    int ry  = rem / RW;
    int yy  = 8 + ry;
    int xx  = 8 + (rem - ry * RW);

    int   pidx = (b * Himg + yy) * Wimg + xx;
    float p    = pred[pidx];

    const float* xv    = x + (size_t)b * (49 * IMGF);
    const float* cbase = xv + 24 * IMGF + (yy * Wimg + xx) * 3;
    float c0 = cbase[0], c1 = cbase[1], c2 = cbase[2];

    // separable warp interpolants: 7 row-pairs (u) and 7 column-offsets (v)
    int ro0[7], ro1[7]; float tyv[7];
    int co[7];          float txv[7];
    #pragma unroll
    for (int u = 0; u < 7; u++) {
        float cy  = fminf(fmaxf((float)yy + p * (float)(u - 3), 0.0f), 255.0f);
        float y0f = floorf(cy);
        tyv[u] = cy - y0f;
        int iy0 = (int)y0f;
        ro0[u] = iy0 * ROWF;
        ro1[u] = min(iy0 + 1, 255) * ROWF;
    }
    #pragma unroll
    for (int v = 0; v < 7; v++) {
        float cx  = fminf(fmaxf((float)xx + p * (float)(v - 3), 0.0f), 255.0f);
        float x0f = floorf(cx);
        float tx  = cx - x0f;
        int   ix0 = (int)x0f;
        if (ix0 >= 255) { ix0 = 254; tx = 1.0f; }   // same bilinear result
        co[v] = ix0 * 3; txv[v] = tx;
    }

    // ---- stage 1: bilinear warp + per-view color loss (register vector) ----
    vf49 cl;
    #pragma unroll
    for (int u = 0; u < 7; u++) {
        #pragma unroll
        for (int v = 0; v < 7; v++) {
            const float* base = xv + (u * 7 + v) * IMGF;
            float s0[6], s1[6];
            __builtin_memcpy(s0, base + ro0[u] + co[v], 24);
            __builtin_memcpy(s1, base + ro1[u] + co[v], 24);
            float tx = txv[v], ty = tyv[u];
            float h0 = s0[0] + tx * (s0[3] - s0[0]);
            float h1 = s0[1] + tx * (s0[4] - s0[1]);
            float h2 = s0[2] + tx * (s0[5] - s0[2]);
            float k0 = s1[0] + tx * (s1[3] - s1[0]);
            float k1 = s1[1] + tx * (s1[4] - s1[1]);
            float k2 = s1[2] + tx * (s1[5] - s1[2]);
            float o0 = h0 + ty * (k0 - h0);
            float o1 = h1 + ty * (k1 - h1);
            float o2 = h2 + ty * (k2 - h2);
            cl[u * 7 + v] = (fabsf(o0 - c0) + fabsf(o1 - c1) + fabsf(o2 - c2))
                            * (1.0f / 3.0f);
        }
    }

    // ---- grad loss (edge-aware smoothness), same pixel ----
    float lx = 0.0f, ly = 0.0f;
    if (xx <= 246) {
        float q3 = cbase[3], q4 = cbase[4], q5 = cbase[5];
        float wx = __expf(-50.0f * (fabsf(q3 - c0) + fabsf(q4 - c1) + fabsf(q5 - c2)));
        lx = wx * fabsf(pred[pidx + 1] - p);
    }
    if (yy <= 246) {
        float r0 = cbase[ROWF], r1 = cbase[ROWF + 1], r2 = cbase[ROWF + 2];
        float wy = __expf(-50.0f * (fabsf(r0 - c0) + fabsf(r1 - c1) + fabsf(r2 - c2)));
        ly = wy * fabsf(pred[pidx + Wimg] - p);
    }

    // ---- stage 2: 3x3 edge-padded gaussian over the 7x7 angular grid ----
    const int epoch = *epoch_p;   // uniform
    vf49 g;
    if (epoch > 0) {
        #pragma unroll
        for (int u = 0; u < 7; u++) {
            #pragma unroll
            for (int v = 0; v < 7; v++) {
                g[u * 7 + v] =
                    0.0751f * cl[CL7(u-1)*7 + CL7(v-1)] + 0.1238f * cl[CL7(u-1)*7 + v] + 0.0751f * cl[CL7(u-1)*7 + CL7(v+1)] +
                    0.1238f * cl[u*7 + CL7(v-1)]        + 0.2042f * cl[u*7 + v]        + 0.1238f * cl[u*7 + CL7(v+1)] +
                    0.0751f * cl[CL7(u+1)*7 + CL7(v-1)] + 0.1238f * cl[CL7(u+1)*7 + v] + 0.0751f * cl[CL7(u+1)*7 + CL7(v+1)];
            }
        }
    } else {
        g = cl;
    }

    // ---- stage 3: stable descending rank + masked tail sum ----
    // rank(n) = #{m<n: g[m]>=g[n]} + #{m>n: g[m]>g[n]}  (stable argsort, desc)
    float yval = y[pidx];
    float tail = 0.0f;
    #pragma unroll
    for (int n = 0; n < NV; n++) {
        int cnt = 0;
        #pragma unroll
        for (int m = 0; m < NV; m++) {
            if (m < n)      cnt += (g[m] >= g[n]) ? 1 : 0;
            else if (m > n) cnt += (g[m] >  g[n]) ? 1 : 0;
        }
        tail += ((float)cnt > yval) ? cl[n] : 0.0f;
    }
    float contrib = tail * (49.0f / (49.0f - yval));

    // ---- single-wave reduction -> 3 double atomics per block ----
    #pragma unroll
    for (int off = 32; off > 0; off >>= 1) {
        contrib += __shfl_down(contrib, off);
        lx      += __shfl_down(lx, off);
        ly      += __shfl_down(ly, off);
    }
    if (tid == 0) {
        atomicAdd(acc + 0, (double)contrib);
        atomicAdd(acc + 1, (double)lx);
        atomicAdd(acc + 2, (double)ly);
    }
}

__global__ void finalize_kernel(const double* __restrict__ acc,
                                float* __restrict__ out)
{
    double cl = acc[0] / 11289600.0;                    // 4*49*240*240
    double gl = (acc[1] + acc[2]) / (2.0 * 229440.0);   // 4*240*239 each
    out[0] = (float)(cl + 0.1 * gl);
}

extern "C" void kernel_launch(void* const* d_in, const int* in_sizes, int n_in,
                              void* d_out, int out_size, void* d_ws, size_t ws_size,
                              hipStream_t stream)
{
    const float* pred  = (const float*)d_in[0];
    const float* x     = (const float*)d_in[1];
    const float* y     = (const float*)d_in[2];
    const int*   epoch = (const int*)d_in[3];
    double* acc = (double*)d_ws;

    hipMemsetAsync(acc, 0, 3 * sizeof(double), stream);
    loss_kernel<<<NBLK, BLK, 0, stream>>>(pred, x, y, epoch, acc);
    finalize_kernel<<<1, 1, 0, stream>>>(acc, (float*)d_out);
}

// Round 5
// 433.023 us; speedup vs baseline: 2.9966x; 2.9966x over previous
//
#include <hip/hip_runtime.h>
#include <math.h>

#define NV    49
#define Himg  256
#define Wimg  256
#define RW    240
#define RWH   (RW*RW)          // 57600
#define NPIX  (4*RWH)          // 230400
#define ROWF  (Wimg*3)         // 768 floats per image row
#define IMGF  (Himg*Wimg*3)    // 196608 floats per view image
#define BLK   64
#define NBLK  (NPIX/BLK)       // 3600

// ---------------------------------------------------------------------------
// One wave per block, one thread per pixel. The wave exclusively owns its 64
// pixels: per-pixel cl[49]/g[49] live in LDS (25 KB), all other state in
// registers with static indexing only. ZERO barriers — every LDS dependency
// is within the single wave (compiler lgkmcnt handles ordering).
// ---------------------------------------------------------------------------
__global__ __launch_bounds__(BLK) void loss_kernel(
    const float* __restrict__ pred, const float* __restrict__ x,
    const float* __restrict__ y, const int* __restrict__ epoch_p,
    double* __restrict__ acc)
{
    __shared__ float s_cl[NV][BLK];   // [view][pixel] -> lane-consecutive, conflict-free
    __shared__ float s_g [NV][BLK];

    const int lane = threadIdx.x;

    // XCD band swizzle: XCD k (= bid%8) gets a contiguous band of blocks
    int lb  = (blockIdx.x & 7) * (NBLK / 8) + (blockIdx.x >> 3);
    int pid = lb * BLK + lane;             // 0..230399 (exact grid)
    int b   = pid / RWH;
    int rem = pid - b * RWH;
    int ry  = rem / RW;
    int yy  = 8 + ry;
    int xx  = 8 + (rem - ry * RW);

    int   pidx = (b * Himg + yy) * Wimg + xx;
    float p    = pred[pidx];

    const float* xv    = x + (size_t)b * (49 * IMGF);
    const float* cbase = xv + 24 * IMGF + (yy * Wimg + xx) * 3;
    float c0 = cbase[0], c1 = cbase[1], c2 = cbase[2];

    // separable warp interpolants (statically indexed -> registers)
    int ro0[7], ro1[7]; float tyv[7];
    int co[7];          float txv[7];
    #pragma unroll
    for (int u = 0; u < 7; u++) {
        float cy  = fminf(fmaxf((float)yy + p * (float)(u - 3), 0.0f), 255.0f);
        float y0f = floorf(cy);
        tyv[u] = cy - y0f;
        int iy0 = (int)y0f;
        ro0[u] = iy0 * ROWF;
        ro1[u] = min(iy0 + 1, 255) * ROWF;
    }
    #pragma unroll
    for (int v = 0; v < 7; v++) {
        float cx  = fminf(fmaxf((float)xx + p * (float)(v - 3), 0.0f), 255.0f);
        float x0f = floorf(cx);
        float tx  = cx - x0f;
        int   ix0 = (int)x0f;
        if (ix0 >= 255) { ix0 = 254; tx = 1.0f; }   // same bilinear result
        co[v] = ix0 * 3; txv[v] = tx;
    }

    // ---- stage 1: bilinear warp + per-view color loss -> LDS immediately ----
    #pragma unroll
    for (int u = 0; u < 7; u++) {
        #pragma unroll
        for (int v = 0; v < 7; v++) {
            const float* base = xv + (u * 7 + v) * IMGF;
            float s0[6], s1[6];
            __builtin_memcpy(s0, base + ro0[u] + co[v], 24);
            __builtin_memcpy(s1, base + ro1[u] + co[v], 24);
            float tx = txv[v], ty = tyv[u];
            float h0 = s0[0] + tx * (s0[3] - s0[0]);
            float h1 = s0[1] + tx * (s0[4] - s0[1]);
            float h2 = s0[2] + tx * (s0[5] - s0[2]);
            float k0 = s1[0] + tx * (s1[3] - s1[0]);
            float k1 = s1[1] + tx * (s1[4] - s1[1]);
            float k2 = s1[2] + tx * (s1[5] - s1[2]);
            float o0 = h0 + ty * (k0 - h0);
            float o1 = h1 + ty * (k1 - h1);
            float o2 = h2 + ty * (k2 - h2);
            s_cl[u * 7 + v][lane] =
                (fabsf(o0 - c0) + fabsf(o1 - c1) + fabsf(o2 - c2)) * (1.0f / 3.0f);
        }
    }

    // ---- grad loss (edge-aware smoothness), same pixel ----
    float lx = 0.0f, ly = 0.0f;
    if (xx <= 246) {
        float q3 = cbase[3], q4 = cbase[4], q5 = cbase[5];
        float wx = __expf(-50.0f * (fabsf(q3 - c0) + fabsf(q4 - c1) + fabsf(q5 - c2)));
        lx = wx * fabsf(pred[pidx + 1] - p);
    }
    if (yy <= 246) {
        float r0 = cbase[ROWF], r1 = cbase[ROWF + 1], r2 = cbase[ROWF + 2];
        float wy = __expf(-50.0f * (fabsf(r0 - c0) + fabsf(r1 - c1) + fabsf(r2 - c2)));
        ly = wy * fabsf(pred[pidx + Wimg] - p);
    }

    // ---- stage 2: 3x3 edge-padded angular gaussian, 3-row register window ----
    const int epoch = *epoch_p;   // uniform
    if (epoch > 0) {
        float rm[7], rc[7], rp[7];
        #pragma unroll
        for (int v = 0; v < 7; v++) {
            rc[v] = s_cl[v][lane];          // row 0
            rp[v] = s_cl[7 + v][lane];      // row 1
            rm[v] = rc[v];                  // clamp(-1) = row 0
        }
        #pragma unroll
        for (int u = 0; u < 7; u++) {
            #pragma unroll
            for (int v = 0; v < 7; v++) {
                int vm = (v == 0) ? 0 : v - 1;
                int vp = (v == 6) ? 6 : v + 1;
                // keep reference's row-major summation order (ties matter)
                s_g[u * 7 + v][lane] =
                    0.0751f * rm[vm] + 0.1238f * rm[v] + 0.0751f * rm[vp] +
                    0.1238f * rc[vm] + 0.2042f * rc[v] + 0.1238f * rc[vp] +
                    0.0751f * rp[vm] + 0.1238f * rp[v] + 0.0751f * rp[vp];
            }
            if (u < 6) {
                #pragma unroll
                for (int v = 0; v < 7; v++) { rm[v] = rc[v]; rc[v] = rp[v]; }
                if (u < 5) {
                    #pragma unroll
                    for (int v = 0; v < 7; v++) rp[v] = s_cl[(u + 2) * 7 + v][lane];
                }
                // u == 5: rp already holds row 6 (clamp)
            }
        }
    }

    // ---- stage 3: blocked stable-descending rank + masked tail sum ----
    // key = (g_bits << 8) | (255 - n): u64 compare gives stable desc order
    float (*key)[BLK] = (epoch > 0) ? s_g : s_cl;
    float yval = y[pidx];
    float tail = 0.0f;
    for (int bi = 0; bi < 7; bi++) {
        unsigned long long kn[7]; int cnt[7];
        #pragma unroll
        for (int j = 0; j < 7; j++) {
            int n = bi * 7 + j;
            kn[j] = (((unsigned long long)__float_as_uint(key[n][lane])) << 8)
                    | (unsigned long long)(255 - n);
            cnt[j] = 0;
        }
        for (int m = 0; m < NV; m++) {
            unsigned long long km =
                (((unsigned long long)__float_as_uint(key[m][lane])) << 8)
                | (unsigned long long)(255 - m);
            #pragma unroll
            for (int j = 0; j < 7; j++)
                cnt[j] += (km > kn[j]) ? 1 : 0;
        }
        #pragma unroll
        for (int j = 0; j < 7; j++) {
            int n = bi * 7 + j;
            tail += ((float)cnt[j] > yval) ? s_cl[n][lane] : 0.0f;
        }
    }
    float contrib = tail * (49.0f / (49.0f - yval));

    // ---- single-wave reduction -> 3 double atomics per block ----
    #pragma unroll
    for (int off = 32; off > 0; off >>= 1) {
        contrib += __shfl_down(contrib, off);
        lx      += __shfl_down(lx, off);
        ly      += __shfl_down(ly, off);
    }
    if (lane == 0) {
        atomicAdd(acc + 0, (double)contrib);
        atomicAdd(acc + 1, (double)lx);
        atomicAdd(acc + 2, (double)ly);
    }
}

__global__ void finalize_kernel(const double* __restrict__ acc,
                                float* __restrict__ out)
{
    double cl = acc[0] / 11289600.0;                    // 4*49*240*240
    double gl = (acc[1] + acc[2]) / (2.0 * 229440.0);   // 4*240*239 each
    out[0] = (float)(cl + 0.1 * gl);
}

extern "C" void kernel_launch(void* const* d_in, const int* in_sizes, int n_in,
                              void* d_out, int out_size, void* d_ws, size_t ws_size,
                              hipStream_t stream)
{
    const float* pred  = (const float*)d_in[0];
    const float* x     = (const float*)d_in[1];
    const float* y     = (const float*)d_in[2];
    const int*   epoch = (const int*)d_in[3];
    double* acc = (double*)d_ws;

    hipMemsetAsync(acc, 0, 3 * sizeof(double), stream);
    loss_kernel<<<NBLK, BLK, 0, stream>>>(pred, x, y, epoch, acc);
    finalize_kernel<<<1, 1, 0, stream>>>(acc, (float*)d_out);
}